// Round 6
// baseline (591.805 us; speedup 1.0000x reference)
//
#include <hip/hip_runtime.h>
#include <hip/hip_bf16.h>

#define HID   256
#define NGATE 1024
#define INP   72
#define STEPS 8
#define TB    64
#define NTHR  1024    // 16 waves; each wave owns 16 gate-cols x all 64 rows
#define LDH   264     // row stride (bf16 elems): 256 + 8 pad (used for h and x)
#define ELEMS_BUF 16896  // TB*LDH elems per LDS buffer (33792 B)

// ---- weight-stream geometry (identical to previous round) -------------------
// Per wave (of 16) per step: 52 fragments x 512 bf16 (1 KB), consumption order:
//   f =  0..31 : WHH  (f = kc*4 + q, kc<8)
//   f = 32..43 : WIH  (f = 32 + kc*4 + q, kc<3; K padded to 96 with zeros)
//   f = 44..51 : WO   (f = 44 + kc; zero for waves 5..15)
#define WSEQ2 32768
#define OFF_WHI 524288
#define OFF_WCI 589824
#define N_ALL   655360
#define OFF_BG_BYTES    1310720
#define OFF_STAGE_BYTES 1314816

typedef short  s8_t  __attribute__((ext_vector_type(8)));
typedef float  f4_t  __attribute__((ext_vector_type(4)));

static __device__ __forceinline__ unsigned short f2bf(float f) {
  unsigned int u = __float_as_uint(f);
  u = (u + 0x7FFFu + ((u >> 16) & 1u)) >> 16;   // RNE
  return (unsigned short)u;
}
static __device__ __forceinline__ float fast_rcp(float x) {
#if __has_builtin(__builtin_amdgcn_rcpf)
  return __builtin_amdgcn_rcpf(x);
#else
  return 1.f / x;
#endif
}
static __device__ __forceinline__ float sigm(float x) {
  return fast_rcp(1.f + __expf(-x));
}
static __device__ __forceinline__ float tanh_(float x) {
  float t = fminf(-2.f * x, 88.f);
  float e = __expf(t);
  return (1.f - e) * fast_rcp(1.f + e);
}

__global__ void prep_kernel(const float* __restrict__ Wih, const float* __restrict__ Whh,
                            const float* __restrict__ bih, const float* __restrict__ bhh,
                            const float* __restrict__ Wh, const float* __restrict__ Wc,
                            const float* __restrict__ Wo,
                            unsigned short* __restrict__ wsh, float* __restrict__ bg) {
  int stride = gridDim.x * blockDim.x;
  for (int i = blockIdx.x * blockDim.x + threadIdx.x; i < N_ALL + NGATE; i += stride) {
    if (i < N_ALL) {
      float v = 0.f;
      if (i < OFF_WHI) {
        int w  = i >> 15;           // wave 0..15
        int r  = i & 32767;
        int f  = r >> 9;            // frag slot 0..63
        int e  = r & 511;
        int lane = e >> 3, j = e & 7;
        int lq = lane >> 4, ln = lane & 15;
        int kk = lq * 8 + j;
        if (f < 32) {                         // WHH
          int kc = f >> 2, q = f & 3;
          int g  = q * 256 + w * 16 + ln;
          int k  = kc * 32 + kk;
          v = Whh[g * HID + k];
        } else if (f < 44) {                  // WIH (K padded to 96)
          int t  = f - 32;
          int kc = t >> 2, q = t & 3;
          int g  = q * 256 + w * 16 + ln;
          int k  = kc * 32 + kk;
          v = (k < INP) ? Wih[g * INP + k] : 0.f;
        } else if (f < 52) {                  // WO (only waves 0..4 real)
          int kc = f - 44;
          int c  = w * 16 + ln;
          int k  = kc * 32 + kk;
          v = (w < 5 && c < INP) ? Wo[c * HID + k] : 0.f;
        }
      } else {
        int base = (i < OFF_WCI) ? OFF_WHI : OFF_WCI;
        const float* Wsrc = (i < OFF_WCI) ? Wh : Wc;
        int jj = i - base;
        int w  = jj >> 12;
        int r  = jj & 4095;
        int kc = r >> 9;
        int e  = r & 511;
        int lane = e >> 3, j = e & 7;
        int lq = lane >> 4, ln = lane & 15;
        int c  = w * 16 + ln;
        int k  = kc * 32 + lq * 8 + j;
        v = Wsrc[c * HID + k];
      }
      wsh[i] = f2bf(v);
    } else {
      int jb = i - N_ALL;
      bg[jb] = bih[jb] + bhh[jb];
    }
  }
}

// One recurrent step. LDS = [hA | x | hB]; h is double-buffered so the cell
// update writes the OTHER buffer -> no barrier between GEMM and cell, and the
// y-phase (waves 0..4) overlaps the next step's h-GEMM (waves 5..15 have no
// trailing barrier). 2 barriers/step instead of 3.
#define STEP(CUR_RD, NXT_RD, NXT_WR, SIDX)                                    \
  {                                                                           \
    f4_t acc[4][4];                                                           \
    _Pragma("unroll")                                                         \
    for (int q = 0; q < 4; ++q)                                               \
      _Pragma("unroll")                                                       \
      for (int rt = 0; rt < 4; ++rt) {                                        \
        const float b = biasg[q];                                             \
        acc[q][rt] = {b, b, b, b};                                            \
      }                                                                       \
    /* phase1: gates += h @ W_hh^T (reads CUR_RD; h ready from prev BAR_h) */ \
    _Pragma("unroll 2")                                                       \
    for (int kc = 0; kc < 8; ++kc) {                                          \
      s8_t a[4];                                                              \
      _Pragma("unroll")                                                       \
      for (int rt = 0; rt < 4; ++rt)                                          \
        a[rt] = *reinterpret_cast<const s8_t*>((CUR_RD) + rt * 16 * LDH + kc * 32); \
      _Pragma("unroll")                                                       \
      for (int q = 0; q < 4; ++q) {                                           \
        s8_t bfr = *reinterpret_cast<const s8_t*>(wst + (kc * 4 + q) * 512);  \
        _Pragma("unroll")                                                     \
        for (int rt = 0; rt < 4; ++rt)                                        \
          acc[q][rt] = __builtin_amdgcn_mfma_f32_16x16x32_bf16(a[rt], bfr, acc[q][rt], 0, 0, 0); \
      }                                                                       \
    }                                                                         \
    __syncthreads(); /* BAR_x: x from previous y-phase now complete */        \
    /* phase2: gates += x @ W_ih^T (x region = imm offset off h_rdA) */       \
    _Pragma("unroll")                                                         \
    for (int kc = 0; kc < 3; ++kc) {                                          \
      s8_t a[4];                                                              \
      _Pragma("unroll")                                                       \
      for (int rt = 0; rt < 4; ++rt)                                          \
        a[rt] = *reinterpret_cast<const s8_t*>(h_rdA + ELEMS_BUF + rt * 16 * LDH + kc * 32); \
      _Pragma("unroll")                                                       \
      for (int q = 0; q < 4; ++q) {                                           \
        s8_t bfr = *reinterpret_cast<const s8_t*>(wst + (32 + kc * 4 + q) * 512); \
        _Pragma("unroll")                                                     \
        for (int rt = 0; rt < 4; ++rt)                                        \
          acc[q][rt] = __builtin_amdgcn_mfma_f32_16x16x32_bf16(a[rt], bfr, acc[q][rt], 0, 0, 0); \
      }                                                                       \
    }                                                                         \
    /* phase3: lane-local cell update; write new h into the OTHER buffer */   \
    _Pragma("unroll")                                                         \
    for (int rt = 0; rt < 4; ++rt)                                            \
      _Pragma("unroll")                                                       \
      for (int r = 0; r < 4; ++r) {                                           \
        float iv = sigm(acc[0][rt][r]);                                       \
        float fv = sigm(acc[1][rt][r]);                                       \
        float gv = tanh_(acc[2][rt][r]);                                      \
        float ov = sigm(acc[3][rt][r]);                                       \
        float cn = fv * c_reg[rt][r] + iv * gv;                               \
        c_reg[rt][r] = cn;                                                    \
        float hv = ov * tanh_(cn);                                            \
        (NXT_WR)[(rt * 16 + r) * LDH] = f2bf(hv);                             \
      }                                                                       \
    __syncthreads(); /* BAR_h: new h complete everywhere */                   \
    /* phase4: y = sigmoid(h_new @ Wo^T + bo); waves 5..15 skip straight      \
       into the next step's phase1 (no trailing barrier) */                   \
    if (w < 5) {                                                              \
      f4_t accy[4];                                                           \
      _Pragma("unroll")                                                       \
      for (int rt = 0; rt < 4; ++rt) accy[rt] = {bov, bov, bov, bov};         \
      _Pragma("unroll 2")                                                     \
      for (int kc = 0; kc < 8; ++kc) {                                        \
        s8_t bfr = *reinterpret_cast<const s8_t*>(wst + (44 + kc) * 512);     \
        _Pragma("unroll")                                                     \
        for (int rt = 0; rt < 4; ++rt) {                                      \
          s8_t a = *reinterpret_cast<const s8_t*>((NXT_RD) + rt * 16 * LDH + kc * 32); \
          accy[rt] = __builtin_amdgcn_mfma_f32_16x16x32_bf16(a, bfr, accy[rt], 0, 0, 0); \
        }                                                                     \
      }                                                                       \
      if (colh0 < INP) {                                                      \
        float* st_base;                                                       \
        if (STAGED) {                                                         \
          st_base = stage + (((size_t)(SIDX) * NB + blockIdx.x) * TB + lq * 4) * INP + colh0; \
        } else {                                                              \
          st_base = out + (size_t)(rb + lq * 4) * (STEPS * INP) + (SIDX) * INP + colh0; \
        }                                                                     \
        unsigned short* x_wr = &lds[ELEMS_BUF + (lq * 4) * LDH + colh0];      \
        _Pragma("unroll")                                                     \
        for (int rt = 0; rt < 4; ++rt)                                        \
          _Pragma("unroll")                                                   \
          for (int r = 0; r < 4; ++r) {                                       \
            float yv = sigm(accy[rt][r]);                                     \
            if (STAGED) {                                                     \
              st_base[(size_t)(rt * 16 + r) * INP] = yv;                      \
            } else {                                                          \
              st_base[(size_t)(rt * 16 + r) * (STEPS * INP)] = yv;            \
            }                                                                 \
            x_wr[(rt * 16 + r) * LDH] = f2bf(yv);                             \
          }                                                                   \
      }                                                                       \
    }                                                                         \
  }

template <int STAGED>
__global__ __launch_bounds__(NTHR, 4) void lstm_kernel(
    const float* __restrict__ z, const unsigned short* __restrict__ wsh,
    const float* __restrict__ bg, const float* __restrict__ bh,
    const float* __restrict__ bc, const float* __restrict__ bo,
    float* __restrict__ out, float* __restrict__ stage, int NB) {
  // [hA (16896) | x (16896) | hB (16896)] elems; all spans from the A-bases
  // stay under the 64 KB ds-offset immediate limit.
  __shared__ unsigned short lds[3 * ELEMS_BUF];

  const int tid  = threadIdx.x;
  const int w    = tid >> 6;     // wave 0..15
  const int lane = tid & 63;
  const int lq   = lane >> 4;
  const int ln   = lane & 15;
  const int rb   = blockIdx.x * TB;
  const int colh0 = w * 16 + ln; // wave's 16 hidden cols

  const unsigned short* wst = wsh + w * WSEQ2 + lane * 8;           // step stream
  const unsigned short* whi = wsh + OFF_WHI + w * 4096 + lane * 8;  // init Wh
  const unsigned short* wci = wsh + OFF_WCI + w * 4096 + lane * 8;  // init Wc

  const unsigned short* h_rdA = &lds[ln * LDH + lq * 8];
  const unsigned short* h_rdB = h_rdA + 2 * ELEMS_BUF;
  unsigned short*       h_wrA = &lds[(lq * 4) * LDH + colh0];
  unsigned short*       h_wrB = h_wrA + 2 * ELEMS_BUF;

  // x starts as zeros (incl. pad cols); zero the whole middle buffer
  for (int i = tid; i < ELEMS_BUF; i += NTHR) lds[ELEMS_BUF + i] = 0;

  // ---------------- init: h = z0@Wh^T + bh, c = z0@Wc^T + bc ----------------
  f4_t acc_h[4], acc_c[4];
  #pragma unroll
  for (int rt = 0; rt < 4; ++rt) {
    acc_h[rt] = {0.f, 0.f, 0.f, 0.f};
    acc_c[rt] = {0.f, 0.f, 0.f, 0.f};
  }

  const float* z_l = z + (size_t)(rb + ln) * HID + lq * 8;

  #pragma unroll 2
  for (int kc = 0; kc < 8; ++kc) {
    s8_t a[4];
    #pragma unroll
    for (int rt = 0; rt < 4; ++rt) {
      f4_t v0 = *reinterpret_cast<const f4_t*>(z_l + rt * 16 * HID + kc * 32);
      f4_t v1 = *reinterpret_cast<const f4_t*>(z_l + rt * 16 * HID + kc * 32 + 4);
      s8_t av;
      av[0] = (short)f2bf(v0[0]); av[1] = (short)f2bf(v0[1]);
      av[2] = (short)f2bf(v0[2]); av[3] = (short)f2bf(v0[3]);
      av[4] = (short)f2bf(v1[0]); av[5] = (short)f2bf(v1[1]);
      av[6] = (short)f2bf(v1[2]); av[7] = (short)f2bf(v1[3]);
      a[rt] = av;
    }
    s8_t bhf = *reinterpret_cast<const s8_t*>(whi + kc * 512);
    s8_t bcf = *reinterpret_cast<const s8_t*>(wci + kc * 512);
    #pragma unroll
    for (int rt = 0; rt < 4; ++rt) {
      acc_h[rt] = __builtin_amdgcn_mfma_f32_16x16x32_bf16(a[rt], bhf, acc_h[rt], 0, 0, 0);
      acc_c[rt] = __builtin_amdgcn_mfma_f32_16x16x32_bf16(a[rt], bcf, acc_c[rt], 0, 0, 0);
    }
  }

  float c_reg[4][4];
  {
    const float bhv = bh[colh0];
    const float bcv = bc[colh0];
    #pragma unroll
    for (int rt = 0; rt < 4; ++rt)
      #pragma unroll
      for (int r = 0; r < 4; ++r) {
        float hv = acc_h[rt][r] + bhv;
        c_reg[rt][r] = acc_c[rt][r] + bcv;
        h_wrA[(rt * 16 + r) * LDH] = f2bf(hv);   // h0 -> buffer A
      }
  }

  float biasg[4];
  #pragma unroll
  for (int q = 0; q < 4; ++q)
    biasg[q] = bg[q * 256 + colh0];

  float bov = 0.f;
  if (w < 5 && colh0 < INP) bov = bo[colh0];

  __syncthreads();   // h0 (A) and x zeros visible

  #pragma unroll 1
  for (int s2 = 0; s2 < STEPS; s2 += 2) {
    STEP(h_rdA, h_rdB, h_wrB, s2);       // A -> B
    STEP(h_rdB, h_rdA, h_wrA, s2 + 1);   // B -> A
  }
}

// stage[((s*NB + b)*TB + r)*72 + c]  ->  out[(b*TB + r)*576 + s*72 + c]
__global__ __launch_bounds__(512) void reorder_kernel(
    const float* __restrict__ stage, float* __restrict__ out, int NB) {
  const int lane = threadIdx.x & 63;
  const int row  = blockIdx.x * 8 + (threadIdx.x >> 6);   // global batch row
  const int b    = row >> 6;          // TB=64
  const int r    = row & 63;
  #pragma unroll
  for (int i = lane; i < STEPS * INP; i += 64) {
    int s = i / INP;
    int c = i - s * INP;
    out[(size_t)row * (STEPS * INP) + i] =
        stage[(((size_t)s * NB + b) * TB + r) * INP + c];
  }
}

extern "C" void kernel_launch(void* const* d_in, const int* in_sizes, int n_in,
                              void* d_out, int out_size, void* d_ws, size_t ws_size,
                              hipStream_t stream) {
  const float* z   = (const float*)d_in[0];
  const float* Wih = (const float*)d_in[1];
  const float* Whh = (const float*)d_in[2];
  const float* bih = (const float*)d_in[3];
  const float* bhh = (const float*)d_in[4];
  const float* Wh  = (const float*)d_in[5];
  const float* bh  = (const float*)d_in[6];
  const float* Wc  = (const float*)d_in[7];
  const float* bc  = (const float*)d_in[8];
  const float* Wo  = (const float*)d_in[9];
  const float* bo  = (const float*)d_in[10];
  float* out = (float*)d_out;

  unsigned short* wsh = (unsigned short*)d_ws;
  float* bg    = (float*)((char*)d_ws + OFF_BG_BYTES);
  float* stage = (float*)((char*)d_ws + OFF_STAGE_BYTES);

  const int B  = in_sizes[0] / HID;   // 32768
  const int NB = B / TB;              // 512

  hipLaunchKernelGGL(prep_kernel, dim3(512), dim3(256), 0, stream,
                     Wih, Whh, bih, bhh, Wh, Wc, Wo, wsh, bg);

  const size_t stage_need = (size_t)OFF_STAGE_BYTES + (size_t)B * STEPS * INP * 4;
  if (ws_size >= stage_need) {
    hipLaunchKernelGGL((lstm_kernel<1>), dim3(NB), dim3(NTHR), 0, stream,
                       z, wsh, bg, bh, bc, bo, out, stage, NB);
    hipLaunchKernelGGL(reorder_kernel, dim3(B / 8), dim3(512), 0, stream,
                       stage, out, NB);
  } else {
    hipLaunchKernelGGL((lstm_kernel<0>), dim3(NB), dim3(NTHR), 0, stream,
                       z, wsh, bg, bh, bc, bo, out, stage, NB);
  }
}

// Round 7
// 572.519 us; speedup vs baseline: 1.0337x; 1.0337x over previous
//
#include <hip/hip_runtime.h>
#include <hip/hip_bf16.h>

#define HID   256
#define NGATE 1024
#define INP   72
#define STEPS 8
#define TB    64
#define NTHR  1024    // 16 waves; each wave owns 16 gate-cols x all 64 rows
#define LDH   264     // h_lds row stride (bf16 elems): 256 + 8 pad
#define LDX   104     // x_lds row stride: 96 + 8 pad

// ---- weight-stream geometry -------------------------------------------------
// Per wave (of 16) per step: 52 fragments x 512 bf16 (1 KB), consumption order:
//   f =  0..31 : WHH  (f = kc*4 + q, kc<8)
//   f = 32..43 : WIH  (f = 32 + kc*4 + q, kc<3; K padded to 96 with zeros)
//   f = 44..51 : WO   (f = 44 + kc; zero for waves 5..15)
// Per-wave stream stride padded to 32768 elems (frags 52..63 zero, unused).
#define WSEQ2 32768
#define OFF_WHI 524288    // init Wh: wave w, frag kc -> OFF_WHI + w*4096 + kc*512
#define OFF_WCI 589824    // init Wc: same layout
#define N_ALL   655360
#define OFF_BG_BYTES    1310720
#define OFF_STAGE_BYTES 1314816

typedef short  s8_t  __attribute__((ext_vector_type(8)));
typedef float  f4_t  __attribute__((ext_vector_type(4)));

static __device__ __forceinline__ unsigned short f2bf(float f) {
  unsigned int u = __float_as_uint(f);
  u = (u + 0x7FFFu + ((u >> 16) & 1u)) >> 16;   // RNE
  return (unsigned short)u;
}
static __device__ __forceinline__ float fast_rcp(float x) {
#if __has_builtin(__builtin_amdgcn_rcpf)
  return __builtin_amdgcn_rcpf(x);
#else
  return 1.f / x;
#endif
}
static __device__ __forceinline__ float sigm(float x) {
  return fast_rcp(1.f + __expf(-x));
}
static __device__ __forceinline__ float tanh_(float x) {
  float t = fminf(-2.f * x, 88.f);
  float e = __expf(t);
  return (1.f - e) * fast_rcp(1.f + e);
}

__global__ void prep_kernel(const float* __restrict__ Wih, const float* __restrict__ Whh,
                            const float* __restrict__ bih, const float* __restrict__ bhh,
                            const float* __restrict__ Wh, const float* __restrict__ Wc,
                            const float* __restrict__ Wo,
                            unsigned short* __restrict__ wsh, float* __restrict__ bg) {
  int stride = gridDim.x * blockDim.x;
  for (int i = blockIdx.x * blockDim.x + threadIdx.x; i < N_ALL + NGATE; i += stride) {
    if (i < N_ALL) {
      float v = 0.f;
      if (i < OFF_WHI) {
        // per-wave fragment stream (16 waves x 64 frag slots, 52 used)
        int w  = i >> 15;           // wave 0..15
        int r  = i & 32767;
        int f  = r >> 9;            // frag slot 0..63
        int e  = r & 511;
        int lane = e >> 3, j = e & 7;
        int lq = lane >> 4, ln = lane & 15;
        int kk = lq * 8 + j;
        if (f < 32) {                         // WHH
          int kc = f >> 2, q = f & 3;
          int g  = q * 256 + w * 16 + ln;
          int k  = kc * 32 + kk;
          v = Whh[g * HID + k];
        } else if (f < 44) {                  // WIH (K padded to 96)
          int t  = f - 32;
          int kc = t >> 2, q = t & 3;
          int g  = q * 256 + w * 16 + ln;
          int k  = kc * 32 + kk;
          v = (k < INP) ? Wih[g * INP + k] : 0.f;
        } else if (f < 52) {                  // WO (only waves 0..4 real)
          int kc = f - 44;
          int c  = w * 16 + ln;
          int k  = kc * 32 + kk;
          v = (w < 5 && c < INP) ? Wo[c * HID + k] : 0.f;
        }
        // f 52..63: zero pad
      } else {
        // init weights Wh / Wc: per wave 8 frags (kc)
        int base = (i < OFF_WCI) ? OFF_WHI : OFF_WCI;
        const float* Wsrc = (i < OFF_WCI) ? Wh : Wc;
        int jj = i - base;
        int w  = jj >> 12;          // 4096 elems per wave
        int r  = jj & 4095;
        int kc = r >> 9;
        int e  = r & 511;
        int lane = e >> 3, j = e & 7;
        int lq = lane >> 4, ln = lane & 15;
        int c  = w * 16 + ln;
        int k  = kc * 32 + lq * 8 + j;
        v = Wsrc[c * HID + k];
      }
      wsh[i] = f2bf(v);
    } else {
      int jb = i - N_ALL;
      bg[jb] = bih[jb] + bhh[jb];
    }
  }
}

// Block: 1024 threads = 16 waves, TB=64 batch rows for the whole recurrence.
// Wave w owns hidden cols [w*16, w*16+16). Identical dataflow to the verified
// 469us version; the ONLY change this round: all streaming global traffic
// (z loads, stage/out stores, reorder) is marked non-temporal so it does not
// allocate/evict in L2 -> the 1.31 MB weight set stays L2-resident and the
// per-step weight-fragment loads become L2 hits instead of L3 misses.
template <int STAGED>
__global__ __launch_bounds__(NTHR, 4) void lstm_kernel(
    const float* __restrict__ z, const unsigned short* __restrict__ wsh,
    const float* __restrict__ bg, const float* __restrict__ bh,
    const float* __restrict__ bc, const float* __restrict__ bo,
    float* __restrict__ out, float* __restrict__ stage, int NB) {
  __shared__ unsigned short h_lds[TB * LDH];
  __shared__ unsigned short x_lds[TB * LDX];

  const int tid  = threadIdx.x;
  const int w    = tid >> 6;     // wave 0..15
  const int lane = tid & 63;
  const int lq   = lane >> 4;
  const int ln   = lane & 15;
  const int rb   = blockIdx.x * TB;
  const int colh0 = w * 16 + ln; // wave's 16 hidden cols

  // packed fragment bases: uniform-per-wave + lane*8 elems (16B/lane)
  const unsigned short* wst = wsh + w * WSEQ2 + lane * 8;           // step stream
  const unsigned short* whi = wsh + OFF_WHI + w * 4096 + lane * 8;  // init Wh
  const unsigned short* wci = wsh + OFF_WCI + w * 4096 + lane * 8;  // init Wc
  const unsigned short* h_rd = &h_lds[ln * LDH + lq * 8];
  const unsigned short* x_rd = &x_lds[ln * LDX + lq * 8];
  unsigned short*       h_wr = &h_lds[(lq * 4) * LDH + colh0];

  for (int i = tid; i < TB * LDX; i += NTHR) x_lds[i] = 0;

  // ---------------- init: h = z0@Wh^T + bh, c = z0@Wc^T + bc ----------------
  f4_t acc_h[4], acc_c[4];
  #pragma unroll
  for (int rt = 0; rt < 4; ++rt) {
    acc_h[rt] = {0.f, 0.f, 0.f, 0.f};
    acc_c[rt] = {0.f, 0.f, 0.f, 0.f};
  }

  const float* z_l = z + (size_t)(rb + ln) * HID + lq * 8;

  #pragma unroll 2
  for (int kc = 0; kc < 8; ++kc) {
    s8_t a[4];
    #pragma unroll
    for (int rt = 0; rt < 4; ++rt) {
      // z is read exactly once per kernel: non-temporal (don't evict weights)
      f4_t v0 = __builtin_nontemporal_load(
          reinterpret_cast<const f4_t*>(z_l + rt * 16 * HID + kc * 32));
      f4_t v1 = __builtin_nontemporal_load(
          reinterpret_cast<const f4_t*>(z_l + rt * 16 * HID + kc * 32 + 4));
      s8_t av;
      av[0] = (short)f2bf(v0[0]); av[1] = (short)f2bf(v0[1]);
      av[2] = (short)f2bf(v0[2]); av[3] = (short)f2bf(v0[3]);
      av[4] = (short)f2bf(v1[0]); av[5] = (short)f2bf(v1[1]);
      av[6] = (short)f2bf(v1[2]); av[7] = (short)f2bf(v1[3]);
      a[rt] = av;
    }
    s8_t bhf = *reinterpret_cast<const s8_t*>(whi + kc * 512);
    s8_t bcf = *reinterpret_cast<const s8_t*>(wci + kc * 512);
    #pragma unroll
    for (int rt = 0; rt < 4; ++rt) {
      acc_h[rt] = __builtin_amdgcn_mfma_f32_16x16x32_bf16(a[rt], bhf, acc_h[rt], 0, 0, 0);
      acc_c[rt] = __builtin_amdgcn_mfma_f32_16x16x32_bf16(a[rt], bcf, acc_c[rt], 0, 0, 0);
    }
  }

  float c_reg[4][4];
  {
    const float bhv = bh[colh0];
    const float bcv = bc[colh0];
    #pragma unroll
    for (int rt = 0; rt < 4; ++rt)
      #pragma unroll
      for (int r = 0; r < 4; ++r) {
        float hv = acc_h[rt][r] + bhv;
        c_reg[rt][r] = acc_c[rt][r] + bcv;
        h_wr[(rt * 16 + r) * LDH] = f2bf(hv);
      }
  }
  __syncthreads();

  float biasg[4];
  #pragma unroll
  for (int q = 0; q < 4; ++q)
    biasg[q] = bg[q * 256 + colh0];

  float bov = 0.f;
  if (w < 5 && colh0 < INP) bov = bo[colh0];   // y col == colh0 for waves 0..4

  for (int s = 0; s < STEPS; ++s) {
    f4_t acc[4][4];                     // [quadrant][row-tile]
    #pragma unroll
    for (int q = 0; q < 4; ++q)
      #pragma unroll
      for (int rt = 0; rt < 4; ++rt) {
        const float b = biasg[q];
        acc[q][rt] = {b, b, b, b};
      }

    // gates += h @ W_hh^T   (K = 256) : frags 0..31
    #pragma unroll 2
    for (int kc = 0; kc < 8; ++kc) {
      s8_t a[4];
      #pragma unroll
      for (int rt = 0; rt < 4; ++rt)
        a[rt] = *reinterpret_cast<const s8_t*>(h_rd + rt * 16 * LDH + kc * 32);
      #pragma unroll
      for (int q = 0; q < 4; ++q) {
        s8_t bfr = *reinterpret_cast<const s8_t*>(wst + (kc * 4 + q) * 512);
        #pragma unroll
        for (int rt = 0; rt < 4; ++rt)
          acc[q][rt] = __builtin_amdgcn_mfma_f32_16x16x32_bf16(a[rt], bfr, acc[q][rt], 0, 0, 0);
      }
    }
    // gates += x @ W_ih^T   (K = 96 padded) : frags 32..43
    #pragma unroll
    for (int kc = 0; kc < 3; ++kc) {
      s8_t a[4];
      #pragma unroll
      for (int rt = 0; rt < 4; ++rt)
        a[rt] = *reinterpret_cast<const s8_t*>(x_rd + rt * 16 * LDX + kc * 32);
      #pragma unroll
      for (int q = 0; q < 4; ++q) {
        s8_t bfr = *reinterpret_cast<const s8_t*>(wst + (32 + kc * 4 + q) * 512);
        #pragma unroll
        for (int rt = 0; rt < 4; ++rt)
          acc[q][rt] = __builtin_amdgcn_mfma_f32_16x16x32_bf16(a[rt], bfr, acc[q][rt], 0, 0, 0);
      }
    }
    __syncthreads();   // all h_lds/x_lds reads done

    // lane-local LSTM cell update; write new h (bf16) to LDS
    #pragma unroll
    for (int rt = 0; rt < 4; ++rt)
      #pragma unroll
      for (int r = 0; r < 4; ++r) {
        float iv = sigm(acc[0][rt][r]);
        float fv = sigm(acc[1][rt][r]);
        float gv = tanh_(acc[2][rt][r]);
        float ov = sigm(acc[3][rt][r]);
        float cn = fv * c_reg[rt][r] + iv * gv;
        c_reg[rt][r] = cn;
        float hv = ov * tanh_(cn);
        h_wr[(rt * 16 + r) * LDH] = f2bf(hv);
      }
    __syncthreads();   // new h visible to all waves

    // y = sigmoid(h_new @ Wo^T + bo); waves 0..4 own the 5 y col-tiles
    if (w < 5) {
      f4_t accy[4];
      #pragma unroll
      for (int rt = 0; rt < 4; ++rt) accy[rt] = {bov, bov, bov, bov};
      #pragma unroll 2
      for (int kc = 0; kc < 8; ++kc) {
        s8_t bfr = *reinterpret_cast<const s8_t*>(wst + (44 + kc) * 512);
        #pragma unroll
        for (int rt = 0; rt < 4; ++rt) {
          s8_t a = *reinterpret_cast<const s8_t*>(h_rd + rt * 16 * LDH + kc * 32);
          accy[rt] = __builtin_amdgcn_mfma_f32_16x16x32_bf16(a, bfr, accy[rt], 0, 0, 0);
        }
      }
      if (colh0 < INP) {
        float* st_base;
        if (STAGED) {
          st_base = stage + (((size_t)s * NB + blockIdx.x) * TB + lq * 4) * INP + colh0;
        } else {
          st_base = out + (size_t)(rb + lq * 4) * (STEPS * INP) + s * INP + colh0;
        }
        unsigned short* x_wr = &x_lds[(lq * 4) * LDX + colh0];
        #pragma unroll
        for (int rt = 0; rt < 4; ++rt)
          #pragma unroll
          for (int r = 0; r < 4; ++r) {
            float yv = sigm(accy[rt][r]);
            // streaming output: non-temporal store (don't evict weights in L2)
            if (STAGED) {
              __builtin_nontemporal_store(yv, &st_base[(size_t)(rt * 16 + r) * INP]);
            } else {
              __builtin_nontemporal_store(yv, &st_base[(size_t)(rt * 16 + r) * (STEPS * INP)]);
            }
            x_wr[(rt * 16 + r) * LDX] = f2bf(yv);
          }
      }
    }
    __syncthreads();   // x_lds writes done before next step's reads
  }
}

// stage[((s*NB + b)*TB + r)*72 + c]  ->  out[(b*TB + r)*576 + s*72 + c]
// Pure stream: fully non-temporal on both sides.
__global__ __launch_bounds__(512) void reorder_kernel(
    const float* __restrict__ stage, float* __restrict__ out, int NB) {
  const int lane = threadIdx.x & 63;
  const int row  = blockIdx.x * 8 + (threadIdx.x >> 6);   // global batch row
  const int b    = row >> 6;          // TB=64
  const int r    = row & 63;
  #pragma unroll
  for (int i = lane; i < STEPS * INP; i += 64) {
    int s = i / INP;
    int c = i - s * INP;
    float v = __builtin_nontemporal_load(
        &stage[(((size_t)s * NB + b) * TB + r) * INP + c]);
    __builtin_nontemporal_store(v, &out[(size_t)row * (STEPS * INP) + i]);
  }
}

extern "C" void kernel_launch(void* const* d_in, const int* in_sizes, int n_in,
                              void* d_out, int out_size, void* d_ws, size_t ws_size,
                              hipStream_t stream) {
  const float* z   = (const float*)d_in[0];
  const float* Wih = (const float*)d_in[1];
  const float* Whh = (const float*)d_in[2];
  const float* bih = (const float*)d_in[3];
  const float* bhh = (const float*)d_in[4];
  const float* Wh  = (const float*)d_in[5];
  const float* bh  = (const float*)d_in[6];
  const float* Wc  = (const float*)d_in[7];
  const float* bc  = (const float*)d_in[8];
  const float* Wo  = (const float*)d_in[9];
  const float* bo  = (const float*)d_in[10];
  float* out = (float*)d_out;

  unsigned short* wsh = (unsigned short*)d_ws;
  float* bg    = (float*)((char*)d_ws + OFF_BG_BYTES);
  float* stage = (float*)((char*)d_ws + OFF_STAGE_BYTES);

  const int B  = in_sizes[0] / HID;   // 32768
  const int NB = B / TB;              // 512

  hipLaunchKernelGGL(prep_kernel, dim3(512), dim3(256), 0, stream,
                     Wih, Whh, bih, bhh, Wh, Wc, Wo, wsh, bg);

  const size_t stage_need = (size_t)OFF_STAGE_BYTES + (size_t)B * STEPS * INP * 4;
  if (ws_size >= stage_need) {
    hipLaunchKernelGGL((lstm_kernel<1>), dim3(NB), dim3(NTHR), 0, stream,
                       z, wsh, bg, bh, bc, bo, out, stage, NB);
    hipLaunchKernelGGL(reorder_kernel, dim3(B / 8), dim3(512), 0, stream,
                       stage, out, NB);
  } else {
    hipLaunchKernelGGL((lstm_kernel<0>), dim3(NB), dim3(NTHR), 0, stream,
                       z, wsh, bg, bh, bc, bo, out, stage, NB);
  }
}